// Round 11
// baseline (75.277 us; speedup 1.0000x reference)
//
#include <hip/hip_runtime.h>
#include <math.h>

#define NPART 8192
#define R2c   0.0025f     /* RADIUS^2 (float32(0.05^2)) */
#define CR2c  0.01f       /* (2*RADIUS)^2 */
#define ACCS  0.005f
#define MAXV  0.05f
#define EPSV  1e-06f
#define NB1D  20          /* bins per axis, width 0.1 over [-1,1] */
#define NBINS 400
#define NPREP 32          /* hist blocks (per-block histograms) */
#define SWBLK 2048        /* sweep blocks: 4 waves = 4 sorted slots each */
#define NREP  8           /* ATTRIBUTION: sweep body repeated 8x (idempotent)
                             so its dispatch exceeds the ~39us harness fills
                             and surfaces in rocprof top-5 with full PMC.
                             Remove next round. */
#define OUT_SCALARS 57344 /* offset of the 6 scalar outputs in d_out */

#define WRED(v) do { \
    v += __shfl_xor(v, 32); v += __shfl_xor(v, 16); v += __shfl_xor(v, 8); \
    v += __shfl_xor(v, 4);  v += __shfl_xor(v, 2);  v += __shfl_xor(v, 1); \
  } while (0)

__device__ __forceinline__ int binof(float v) {
  int b = (int)floorf((v + 1.0f) * 10.0f);
  return b < 0 ? 0 : (b > 19 ? 19 : b);
}

// ---------------------------------------------------------------- K1 ------
// hist only (unchanged from R10).
__global__ __launch_bounds__(256) void hist_kernel(
    const float* __restrict__ x, int* __restrict__ bhistT)
{
  __shared__ int h[NBINS];
  const int t = threadIdx.x;
  h[t] = 0;
  if (t + 256 < NBINS) h[t + 256] = 0;
  __syncthreads();

  const int i = blockIdx.x * 256 + t;
  const int bid = binof(x[i * 7 + 1]) * NB1D + binof(x[i * 7]);
  atomicAdd(&h[bid], 1); /* LDS atomic, order-independent count */
  __syncthreads();

  bhistT[t * NPREP + blockIdx.x] = h[t];
  if (t + 256 < NBINS) bhistT[(t + 256) * NPREP + blockIdx.x] = h[t + 256];
}

// ---------------------------------------------------------------- K2 ------
// direct placement (unchanged from R10).
__global__ __launch_bounds__(256) void place_kernel(
    const float* __restrict__ x, const float* __restrict__ wn,
    const int* __restrict__ bhistT, float4* __restrict__ srec,
    int* __restrict__ binstart)
{
  __shared__ int sTot[512];
  __shared__ int sIncl[512];
  __shared__ int sPre[512];
  __shared__ int sBid[256];
  const int t = threadIdx.x;
  const int me = blockIdx.x;

  for (int e = t; e < 512; e += 256) {
    int tot = 0, pre = 0;
    if (e < NBINS) {
      const int4* hp = (const int4*)(bhistT + e * NPREP);
#pragma unroll
      for (int q = 0; q < 8; ++q) {
        int4 v = hp[q];
        int b4 = q * 4;
        tot += v.x + v.y + v.z + v.w;
        pre += ((b4 + 0 < me) ? v.x : 0) + ((b4 + 1 < me) ? v.y : 0) +
               ((b4 + 2 < me) ? v.z : 0) + ((b4 + 3 < me) ? v.w : 0);
      }
    }
    sTot[e] = tot; sIncl[e] = tot; sPre[e] = pre;
  }
  __syncthreads();

  for (int off = 1; off < 512; off <<= 1) {
    int v0 = sIncl[t]       + ((t       >= off) ? sIncl[t - off]       : 0);
    int v1 = sIncl[t + 256] + ((t + 256 >= off) ? sIncl[t + 256 - off] : 0);
    __syncthreads();
    sIncl[t] = v0; sIncl[t + 256] = v1;
    __syncthreads();
  }

  const int i = me * 256 + t;
  const float* xi = x + i * 7;
  float v0 = xi[0], v1 = xi[1], v2 = xi[2], v3 = xi[3];
  float v4 = xi[4], v5 = xi[5], v6 = xi[6];
  float ci = (v4 > 0.5f) ? 1.0f : 0.0f;
  float y[4];
#pragma unroll
  for (int c = 0; c < 4; ++c) {
    float s = v0 * wn[c];
    s += v1 * wn[4 + c];
    s += v2 * wn[8 + c];
    s += v3 * wn[12 + c];
    s += v4 * wn[16 + c];
    s += v5 * wn[20 + c];
    s += v6 * wn[24 + c];
    y[c] = s;
  }
  const int bid = binof(v1) * NB1D + binof(v0);
  sBid[t] = bid;
  __syncthreads();

  int rank = 0;
  for (int k = 0; k < 256; ++k)
    rank += (k < t && sBid[k] == bid) ? 1 : 0;

  const int excl = sIncl[bid] - sTot[bid];
  const int slot = excl + sPre[bid] + rank;
  srec[slot * 2]     = make_float4(v0, v1, y[0], y[1]);
  srec[slot * 2 + 1] = make_float4(y[2], y[3], ci, __int_as_float(i));

  if (me == 0) {
    for (int e = t; e < NBINS; e += 256) binstart[e] = sIncl[e] - sTot[e];
    if (t == 0) binstart[NBINS] = NPART;
  }
}

// ---------------------------------------------------------------- K3 ------
// sweep: IDENTICAL algorithm to R10, wrapped in an NREP attribution loop.
// Opaque pointer copies per rep (empty asm "+v") prevent the compiler from
// hoisting the loop-invariant body -- each rep re-executes the full
// front-end + sweep + epilogue, writing identical values (idempotent).
__global__ __launch_bounds__(256, 8) void sweep_kernel(
    const float* __restrict__ x_in, const float* __restrict__ wself,
    const float* __restrict__ bvec, const int* __restrict__ binstart_in,
    const float4* __restrict__ srec_in, float* __restrict__ out_in,
    float* __restrict__ partials_in)
{
  __shared__ float s_scal[4][6];
  const int lane = threadIdx.x & 63, wave = threadIdx.x >> 6;
  const int swz = (blockIdx.x & 7) * (SWBLK / 8) + (blockIdx.x >> 3);
  const int s = swz * 4 + wave;

  for (int rep = 0; rep < NREP; ++rep) {
    const float* x = x_in;
    const int* binstart = binstart_in;
    const float4* srec = srec_in;
    float* out = out_in;
    float* partials = partials_in;
    asm volatile("" : "+v"(x), "+v"(binstart), "+v"(srec), "+v"(out),
                      "+v"(partials));
    __syncthreads(); /* protect s_scal across reps */

    const float4 r0 = srec[s * 2];
    const float4 r1 = srec[s * 2 + 1];
    const float px = r0.x, py = r0.y, ci = r1.z;
    const int orig = __float_as_int(r1.w);
    const int bx = binof(px), by = binof(py);
    const int xlo = (bx > 0) ? bx - 1 : 0, xhi = (bx < 19) ? bx + 1 : 19;
    const int rm = by - 1, rp = by + 1;
    const int b0 = (rm >= 0) ? binstart[rm * NB1D + xlo] : 0;
    const int e0 = (rm >= 0) ? binstart[rm * NB1D + xhi + 1] : 0;
    const int b1 = binstart[by * NB1D + xlo];
    const int e1 = binstart[by * NB1D + xhi + 1];
    const int b2 = (rp < NB1D) ? binstart[rp * NB1D + xlo] : 0;
    const int e2 = (rp < NB1D) ? binstart[rp * NB1D + xhi + 1] : 0;
    const int len0 = e0 - b0, len1 = e1 - b1;
    const int total = len0 + len1 + (e2 - b2);

#define IA(O, DST) { int t1 = (O) - len0, t2 = (O) - len0 - len1; \
      DST = b0 + (O); DST = (t1 >= 0) ? (b1 + t1) : DST; \
      DST = (t2 >= 0) ? (b2 + t2) : DST; }

    float nsx = 0.f, nsy = 0.f, nsz = 0.f, nsw = 0.f;
    float pk = 0.f; /* cons*2^16 + cnb*2^8 + cnt (all <256 -> exact) */

    int o = lane;
    bool v = o < total;
    int ia; IA(v ? o : 0, ia); if (!v) ia = 0;
    float4 a0 = srec[ia * 2];
    float4 a1 = srec[ia * 2 + 1];
    const int nchunk = (total + 63) >> 6;
    for (int k = 0; k < nchunk; ++k) {
      int on = o + 64;
      bool vn = on < total;
      int ian; IA(vn ? on : 0, ian); if (!vn) ian = 0;
      float4 n0 = srec[ian * 2];          /* prefetch next chunk */
      float4 n1 = srec[ian * 2 + 1];
      float dx = __fsub_rn(px, a0.x), dy = __fsub_rn(py, a0.y);
      float d2 = __fadd_rn(__fmul_rn(dx, dx), __fmul_rn(dy, dy));
      bool valid = v && (__float_as_int(a1.w) != orig);
      bool inCR = valid && (d2 < CR2c);
      bool inR  = valid && (d2 < R2c);
      float cj = a1.z;
      pk += (inCR ? cj * 65536.f : 0.f) + (inR ? (cj * 256.f + 1.f) : 0.f);
      nsx += inR ? a0.z : 0.f;
      nsy += inR ? a0.w : 0.f;
      nsz += inR ? a1.x : 0.f;
      nsw += inR ? a1.y : 0.f;
      o = on; v = vn; a0 = n0; a1 = n1;
    }
#undef IA

    WRED(nsx); WRED(nsy); WRED(nsz); WRED(nsw); WRED(pk);

    if (lane == 0) {
      float consCR = floorf(pk * 1.52587890625e-05f);      /* 2^-16 */
      float rem = pk - consCR * 65536.f;
      float cnbR = floorf(rem * 0.00390625f);              /* 2^-8  */
      float cntR = rem - cnbR * 256.f;

      const float* xi = x + orig * 7;
      float vx = xi[2], vy = xi[3], typ = xi[4], x5 = xi[5], x6 = xi[6];
      float h0 = bvec[0] + px * wself[0] + py * wself[4] + vx * wself[8] +
                 vy * wself[12] + typ * wself[16] + x5 * wself[20] +
                 x6 * wself[24] + nsx;
      float h1 = bvec[1] + px * wself[1] + py * wself[5] + vx * wself[9] +
                 vy * wself[13] + typ * wself[17] + x5 * wself[21] +
                 x6 * wself[25] + nsy;
      float h2 = bvec[2] + px * wself[2] + py * wself[6] + vx * wself[10] +
                 vy * wself[14] + typ * wself[18] + x5 * wself[22] +
                 x6 * wself[26] + nsz;
      float h3 = bvec[3] + px * wself[3] + py * wself[7] + vx * wself[11] +
                 vy * wself[15] + typ * wself[19] + x5 * wself[23] +
                 x6 * wself[27] + nsw;
      float scm = ACCS * ci;
      h0 *= scm; h1 *= scm; h2 *= scm; h3 *= scm;
      float nvx = fminf(fmaxf(vx + h0, -MAXV), MAXV);
      float nvy = fminf(fmaxf(vy + h1, -MAXV), MAXV);
      float npx = px + nvx, npy = py + nvy;
      float border = 0.f;
      float ax = fabsf(npx), ay = fabsf(npy);
      if (ax > 1.0f) border += logf(ax + EPSV);
      if (ay > 1.0f) border += logf(ay + EPSV);
      bool dead = (ci > 0.5f) && (cnbR < 2.5f);
      bool consumed = (ci < 0.5f) && (consCR > 4.5f);
      float keep = (dead || consumed) ? 0.f : 1.f;
      float* orow = out + (size_t)orig * 7;
      orow[0] = npx * keep; orow[1] = npy * keep;
      orow[2] = nvx * keep; orow[3] = nvy * keep;
      orow[4] = typ * keep; orow[5] = h2 * keep; orow[6] = h3 * keep;
      s_scal[wave][0] = fabsf(nvx);
      s_scal[wave][1] = fabsf(nvy);
      s_scal[wave][2] = border;
      s_scal[wave][3] = consumed ? 1.f : 0.f;
      s_scal[wave][4] = dead ? 1.f : 0.f;
      s_scal[wave][5] = cntR - cnbR;
    }
    __syncthreads();
    if (threadIdx.x == 0) {
#pragma unroll
      for (int k = 0; k < 6; ++k)
        partials[k * SWBLK + swz] =
            s_scal[0][k] + s_scal[1][k] + s_scal[2][k] + s_scal[3][k];
    }
  }
}

// ---------------------------------------------------------------- K4 ------
// Deterministic reduction (unchanged from R10).
__global__ __launch_bounds__(384) void reduce_kernel(
    const float* __restrict__ partials, float* __restrict__ out)
{
  int wave = threadIdx.x >> 6, lane = threadIdx.x & 63;
  if (wave >= 6) return;
  float s = 0.f;
  for (int bidx = lane; bidx < SWBLK; bidx += 64)
    s += partials[wave * SWBLK + bidx];
  WRED(s);
  if (lane == 0) {
    float v = s;
    if (wave < 2) v = s * (1.0f / 8192.0f); /* vel_bonus = mean */
    out[OUT_SCALARS + wave] = v;
  }
}

// ------------------------------------------------------------- launch -----
extern "C" void kernel_launch(void* const* d_in, const int* in_sizes, int n_in,
                              void* d_out, int out_size, void* d_ws, size_t ws_size,
                              hipStream_t stream)
{
  const float* x      = (const float*)d_in[0];
  const float* wself  = (const float*)d_in[1];
  const float* wneigh = (const float*)d_in[2];
  const float* bvec   = (const float*)d_in[3];
  float* out = (float*)d_out;
  float* ws  = (float*)d_ws;

  float4* srec  = (float4*)ws;                      /* 8N floats          */
  int* bhistT   = (int*)(ws + 8 * NPART);           /* NBINS*NPREP ints   */
  int* binstart = bhistT + NBINS * NPREP;           /* NBINS+1 ints       */
  float* partials = (float*)(binstart + NBINS + 65);/* 6*SWBLK floats     */

  hipLaunchKernelGGL(hist_kernel, dim3(NPREP), dim3(256), 0, stream,
                     x, bhistT);
  hipLaunchKernelGGL(place_kernel, dim3(NPREP), dim3(256), 0, stream,
                     x, wneigh, bhistT, srec, binstart);
  hipLaunchKernelGGL(sweep_kernel, dim3(SWBLK), dim3(256), 0, stream,
                     x, wself, bvec, binstart, srec, out, partials);
  hipLaunchKernelGGL(reduce_kernel, dim3(1), dim3(384), 0, stream,
                     partials, out);
}

// Round 12
// 33.843 us; speedup vs baseline: 2.2243x; 2.2243x over previous
//
#include <hip/hip_runtime.h>
#include <math.h>

#define NPART 8192
#define R2c   0.0025f     /* RADIUS^2 (float32(0.05^2)) */
#define CR2c  0.01f       /* (2*RADIUS)^2 */
#define ACCS  0.005f
#define MAXV  0.05f
#define EPSV  1e-06f
#define NB1D  20          /* bins per axis, width 0.1 over [-1,1] */
#define NBINS 400
#define NPLACE 32         /* place blocks (256 rows each) */
#define SWBLK 2048        /* sweep blocks: 4 waves = 4 sorted slots each */
#define OUT_SCALARS 57344 /* offset of the 6 scalar outputs in d_out */

#define WRED(v) do { \
    v += __shfl_xor(v, 32); v += __shfl_xor(v, 16); v += __shfl_xor(v, 8); \
    v += __shfl_xor(v, 4);  v += __shfl_xor(v, 2);  v += __shfl_xor(v, 1); \
  } while (0)

__device__ __forceinline__ int binof(float v) {
  int b = (int)floorf((v + 1.0f) * 10.0f);
  return b < 0 ? 0 : (b > 19 ? 19 : b);
}

// ---------------------------------------------------------------- K1 ------
// fused hist+place (R12: the separate hist kernel cost a ~6us dispatch
// boundary -- R11 attribution showed dispatch floor dominates all kernels).
// Each of the 32 blocks REDUNDANTLY histograms all 8192 rows into two LDS
// histograms split at its own base row: hPre (rows < me*256 = "blocks
// before me") and hPost. tot = hPre+hPost; Hillis-Steele scan -> global bin
// prefix; stable intra-block rank via 256-iter LDS broadcast loop; final
// slot = excl[bid] + hPre[bid] + rank -- EXACTLY R10's layout, so srec /
// binstart are bit-identical. Fully deterministic, no global atomics.
__global__ __launch_bounds__(256) void place_kernel(
    const float* __restrict__ x, const float* __restrict__ wn,
    float4* __restrict__ srec, int* __restrict__ binstart)
{
  __shared__ int hPre[512];
  __shared__ int hPost[512];
  __shared__ int sIncl[512];
  __shared__ int sBid[256];
  const int t = threadIdx.x;
  const int me = blockIdx.x;
  const int base = me * 256;

  hPre[t] = 0; hPre[t + 256] = 0;
  hPost[t] = 0; hPost[t + 256] = 0;
  __syncthreads();

  for (int i = t; i < NPART; i += 256) {
    int bid = binof(x[i * 7 + 1]) * NB1D + binof(x[i * 7]);
    atomicAdd(((i < base) ? hPre : hPost) + bid, 1); /* LDS, order-indep */
  }
  __syncthreads();

  sIncl[t]       = hPre[t] + hPost[t];
  sIncl[t + 256] = hPre[t + 256] + hPost[t + 256];
  __syncthreads();
  for (int off = 1; off < 512; off <<= 1) {
    int v0 = sIncl[t]       + ((t       >= off) ? sIncl[t - off]       : 0);
    int v1 = sIncl[t + 256] + ((t + 256 >= off) ? sIncl[t + 256 - off] : 0);
    __syncthreads();
    sIncl[t] = v0; sIncl[t + 256] = v1;
    __syncthreads();
  }

  /* my row: record + bin */
  const int i = base + t;
  const float* xi = x + i * 7;
  float v0 = xi[0], v1 = xi[1], v2 = xi[2], v3 = xi[3];
  float v4 = xi[4], v5 = xi[5], v6 = xi[6];
  float ci = (v4 > 0.5f) ? 1.0f : 0.0f;
  float y[4];
#pragma unroll
  for (int c = 0; c < 4; ++c) {
    float s = v0 * wn[c];
    s += v1 * wn[4 + c];
    s += v2 * wn[8 + c];
    s += v3 * wn[12 + c];
    s += v4 * wn[16 + c];
    s += v5 * wn[20 + c];
    s += v6 * wn[24 + c];
    y[c] = s;
  }
  const int bid = binof(v1) * NB1D + binof(v0);
  sBid[t] = bid;
  __syncthreads();

  int rank = 0;
  for (int k = 0; k < 256; ++k)
    rank += (k < t && sBid[k] == bid) ? 1 : 0;  /* LDS broadcast loop */

  const int tot = hPre[bid] + hPost[bid];
  const int excl = sIncl[bid] - tot;
  const int slot = excl + hPre[bid] + rank;
  srec[slot * 2]     = make_float4(v0, v1, y[0], y[1]);
  srec[slot * 2 + 1] = make_float4(y[2], y[3], ci, __int_as_float(i));

  if (me == 0) {
    for (int e = t; e < NBINS; e += 256)
      binstart[e] = sIncl[e] - (hPre[e] + hPost[e]);
    if (t == 0) binstart[NBINS] = NPART;
  }
}

// ---------------------------------------------------------------- K2 ------
// sweep (R10 form, attribution NREP removed). One wave per sorted slot,
// unified ordinal loop over the 3 contiguous 3x3-window segments, rolling
// prefetch. Self excluded via index compare; dist2 in the reference's
// non-contracted mul/mul/add form. XCD-swizzled blockIdx; partials
// transposed [6][SWBLK]. R11 PMC: 5.7-6.4us, VALUBusy 70.8% -> issue-bound,
// near its arithmetic floor. No fences, no global atomics (R5/R8 lessons).
__global__ __launch_bounds__(256, 8) void sweep_kernel(
    const float* __restrict__ x, const float* __restrict__ wself,
    const float* __restrict__ bvec, const int* __restrict__ binstart,
    const float4* __restrict__ srec, float* __restrict__ out,
    float* __restrict__ partials)
{
  __shared__ float s_scal[4][6];
  const int lane = threadIdx.x & 63, wave = threadIdx.x >> 6;
  const int swz = (blockIdx.x & 7) * (SWBLK / 8) + (blockIdx.x >> 3);
  const int s = swz * 4 + wave;
  const float4 r0 = srec[s * 2];
  const float4 r1 = srec[s * 2 + 1];
  const float px = r0.x, py = r0.y, ci = r1.z;
  const int orig = __float_as_int(r1.w);
  const int bx = binof(px), by = binof(py);
  const int xlo = (bx > 0) ? bx - 1 : 0, xhi = (bx < 19) ? bx + 1 : 19;
  const int rm = by - 1, rp = by + 1;
  const int b0 = (rm >= 0) ? binstart[rm * NB1D + xlo] : 0;
  const int e0 = (rm >= 0) ? binstart[rm * NB1D + xhi + 1] : 0;
  const int b1 = binstart[by * NB1D + xlo];
  const int e1 = binstart[by * NB1D + xhi + 1];
  const int b2 = (rp < NB1D) ? binstart[rp * NB1D + xlo] : 0;
  const int e2 = (rp < NB1D) ? binstart[rp * NB1D + xhi + 1] : 0;
  const int len0 = e0 - b0, len1 = e1 - b1;
  const int total = len0 + len1 + (e2 - b2);

#define IA(O, DST) { int t1 = (O) - len0, t2 = (O) - len0 - len1; \
    DST = b0 + (O); DST = (t1 >= 0) ? (b1 + t1) : DST; \
    DST = (t2 >= 0) ? (b2 + t2) : DST; }

  float nsx = 0.f, nsy = 0.f, nsz = 0.f, nsw = 0.f;
  float pk = 0.f; /* cons*2^16 + cnb*2^8 + cnt (all <256 -> exact) */

  int o = lane;
  bool v = o < total;
  int ia; IA(v ? o : 0, ia); if (!v) ia = 0;
  float4 a0 = srec[ia * 2];
  float4 a1 = srec[ia * 2 + 1];
  const int nchunk = (total + 63) >> 6;
  for (int k = 0; k < nchunk; ++k) {
    int on = o + 64;
    bool vn = on < total;
    int ian; IA(vn ? on : 0, ian); if (!vn) ian = 0;
    float4 n0 = srec[ian * 2];          /* prefetch next chunk */
    float4 n1 = srec[ian * 2 + 1];
    float dx = __fsub_rn(px, a0.x), dy = __fsub_rn(py, a0.y);
    float d2 = __fadd_rn(__fmul_rn(dx, dx), __fmul_rn(dy, dy));
    bool valid = v && (__float_as_int(a1.w) != orig);
    bool inCR = valid && (d2 < CR2c);
    bool inR  = valid && (d2 < R2c);
    float cj = a1.z;
    pk += (inCR ? cj * 65536.f : 0.f) + (inR ? (cj * 256.f + 1.f) : 0.f);
    nsx += inR ? a0.z : 0.f;
    nsy += inR ? a0.w : 0.f;
    nsz += inR ? a1.x : 0.f;
    nsw += inR ? a1.y : 0.f;
    o = on; v = vn; a0 = n0; a1 = n1;
  }
#undef IA

  WRED(nsx); WRED(nsy); WRED(nsz); WRED(nsw); WRED(pk);

  if (lane == 0) {
    /* exact unpack (all fields integer-valued, < 2^24) */
    float consCR = floorf(pk * 1.52587890625e-05f);      /* 2^-16 */
    float rem = pk - consCR * 65536.f;
    float cnbR = floorf(rem * 0.00390625f);              /* 2^-8  */
    float cntR = rem - cnbR * 256.f;

    const float* xi = x + orig * 7;
    float vx = xi[2], vy = xi[3], typ = xi[4], x5 = xi[5], x6 = xi[6];
    float h0 = bvec[0] + px * wself[0] + py * wself[4] + vx * wself[8] +
               vy * wself[12] + typ * wself[16] + x5 * wself[20] +
               x6 * wself[24] + nsx;
    float h1 = bvec[1] + px * wself[1] + py * wself[5] + vx * wself[9] +
               vy * wself[13] + typ * wself[17] + x5 * wself[21] +
               x6 * wself[25] + nsy;
    float h2 = bvec[2] + px * wself[2] + py * wself[6] + vx * wself[10] +
               vy * wself[14] + typ * wself[18] + x5 * wself[22] +
               x6 * wself[26] + nsz;
    float h3 = bvec[3] + px * wself[3] + py * wself[7] + vx * wself[11] +
               vy * wself[15] + typ * wself[19] + x5 * wself[23] +
               x6 * wself[27] + nsw;
    float scm = ACCS * ci;
    h0 *= scm; h1 *= scm; h2 *= scm; h3 *= scm;
    float nvx = fminf(fmaxf(vx + h0, -MAXV), MAXV);
    float nvy = fminf(fmaxf(vy + h1, -MAXV), MAXV);
    float npx = px + nvx, npy = py + nvy;
    float border = 0.f;
    float ax = fabsf(npx), ay = fabsf(npy);
    if (ax > 1.0f) border += logf(ax + EPSV);
    if (ay > 1.0f) border += logf(ay + EPSV);
    bool dead = (ci > 0.5f) && (cnbR < 2.5f);
    bool consumed = (ci < 0.5f) && (consCR > 4.5f);
    float keep = (dead || consumed) ? 0.f : 1.f;
    float* orow = out + (size_t)orig * 7;
    orow[0] = npx * keep; orow[1] = npy * keep;
    orow[2] = nvx * keep; orow[3] = nvy * keep;
    orow[4] = typ * keep; orow[5] = h2 * keep; orow[6] = h3 * keep;
    s_scal[wave][0] = fabsf(nvx);
    s_scal[wave][1] = fabsf(nvy);
    s_scal[wave][2] = border;
    s_scal[wave][3] = consumed ? 1.f : 0.f;
    s_scal[wave][4] = dead ? 1.f : 0.f;
    s_scal[wave][5] = cntR - cnbR;
  }
  __syncthreads();
  if (threadIdx.x == 0) {
#pragma unroll
    for (int k = 0; k < 6; ++k)
      partials[k * SWBLK + swz] =
          s_scal[0][k] + s_scal[1][k] + s_scal[2][k] + s_scal[3][k];
  }
}

// ---------------------------------------------------------------- K3 ------
// Deterministic reduction, coalesced transposed partials (unchanged).
// Separate launch = cross-block visibility without fences (R5/R8 lessons).
__global__ __launch_bounds__(384) void reduce_kernel(
    const float* __restrict__ partials, float* __restrict__ out)
{
  int wave = threadIdx.x >> 6, lane = threadIdx.x & 63;
  if (wave >= 6) return;
  float s = 0.f;
  for (int bidx = lane; bidx < SWBLK; bidx += 64)
    s += partials[wave * SWBLK + bidx];
  WRED(s);
  if (lane == 0) {
    float v = s;
    if (wave < 2) v = s * (1.0f / 8192.0f); /* vel_bonus = mean */
    out[OUT_SCALARS + wave] = v;
  }
}

// ------------------------------------------------------------- launch -----
extern "C" void kernel_launch(void* const* d_in, const int* in_sizes, int n_in,
                              void* d_out, int out_size, void* d_ws, size_t ws_size,
                              hipStream_t stream)
{
  const float* x      = (const float*)d_in[0];
  const float* wself  = (const float*)d_in[1];
  const float* wneigh = (const float*)d_in[2];
  const float* bvec   = (const float*)d_in[3];
  float* out = (float*)d_out;
  float* ws  = (float*)d_ws;

  float4* srec  = (float4*)ws;                      /* 8N floats          */
  int* binstart = (int*)(ws + 8 * NPART);           /* NBINS+1 ints       */
  float* partials = (float*)(binstart + NBINS + 65);/* 6*SWBLK floats     */

  hipLaunchKernelGGL(place_kernel, dim3(NPLACE), dim3(256), 0, stream,
                     x, wneigh, srec, binstart);
  hipLaunchKernelGGL(sweep_kernel, dim3(SWBLK), dim3(256), 0, stream,
                     x, wself, bvec, binstart, srec, out, partials);
  hipLaunchKernelGGL(reduce_kernel, dim3(1), dim3(384), 0, stream,
                     partials, out);
}

// Round 13
// 33.710 us; speedup vs baseline: 2.2331x; 1.0039x over previous
//
#include <hip/hip_runtime.h>
#include <math.h>

#define NPART 8192
#define R2c   0.0025f     /* RADIUS^2 (float32(0.05^2)) */
#define CR2c  0.01f       /* (2*RADIUS)^2 */
#define ACCS  0.005f
#define MAXV  0.05f
#define EPSV  1e-06f
#define NB1D  20          /* bins per axis, width 0.1 over [-1,1] */
#define NBINS 400
#define NPLACE 32         /* place blocks (256 rows each) */
#define SWBLK 2048        /* sweep blocks: 4 waves = 4 sorted slots each */
#define OUT_SCALARS 57344 /* offset of the 6 scalar outputs in d_out */

#define WRED(v) do { \
    v += __shfl_xor(v, 32); v += __shfl_xor(v, 16); v += __shfl_xor(v, 8); \
    v += __shfl_xor(v, 4);  v += __shfl_xor(v, 2);  v += __shfl_xor(v, 1); \
  } while (0)

__device__ __forceinline__ int binof(float v) {
  int b = (int)floorf((v + 1.0f) * 10.0f);
  return b < 0 ? 0 : (b > 19 ? 19 : b);
}

// ---------------------------------------------------------------- K1 ------
// fused hist+place+META (R13). As R12 (redundant dual-LDS-histogram per
// block -> stable slot, bit-identical sorted layout), plus: while the FULL
// bin prefix sits in LDS, precompute each row's sweep front-end into a 32B
// meta[slot] record: {b0, b1adj, b2adj, pack(len0,l01) | px, py, ci|orig,
// total}. Sweep then needs NO self srec read, NO bin calc, NO 6 binstart
// loads -- its cold cross-XCD front-end chain (3-4 dependent rounds, ~6us
// of R11's measured 11.6us cold sweep) collapses to one 32B line. binstart
// global buffer dropped entirely (no consumer left).
__global__ __launch_bounds__(256) void place_kernel(
    const float* __restrict__ x, const float* __restrict__ wn,
    float4* __restrict__ srec, float4* __restrict__ meta)
{
  __shared__ int hPre[512];
  __shared__ int hPost[512];
  __shared__ int sIncl[512];
  __shared__ int sBid[256];
  const int t = threadIdx.x;
  const int me = blockIdx.x;
  const int base = me * 256;

  hPre[t] = 0; hPre[t + 256] = 0;
  hPost[t] = 0; hPost[t + 256] = 0;
  __syncthreads();

  for (int i = t; i < NPART; i += 256) {
    int bid = binof(x[i * 7 + 1]) * NB1D + binof(x[i * 7]);
    atomicAdd(((i < base) ? hPre : hPost) + bid, 1); /* LDS, order-indep */
  }
  __syncthreads();

  sIncl[t]       = hPre[t] + hPost[t];
  sIncl[t + 256] = hPre[t + 256] + hPost[t + 256];
  __syncthreads();
  for (int off = 1; off < 512; off <<= 1) {
    int v0 = sIncl[t]       + ((t       >= off) ? sIncl[t - off]       : 0);
    int v1 = sIncl[t + 256] + ((t + 256 >= off) ? sIncl[t + 256 - off] : 0);
    __syncthreads();
    sIncl[t] = v0; sIncl[t + 256] = v1;
    __syncthreads();
  }

  /* my row: record + bin */
  const int i = base + t;
  const float* xi = x + i * 7;
  float v0 = xi[0], v1 = xi[1], v2 = xi[2], v3 = xi[3];
  float v4 = xi[4], v5 = xi[5], v6 = xi[6];
  float ci = (v4 > 0.5f) ? 1.0f : 0.0f;
  float y[4];
#pragma unroll
  for (int c = 0; c < 4; ++c) {
    float s = v0 * wn[c];
    s += v1 * wn[4 + c];
    s += v2 * wn[8 + c];
    s += v3 * wn[12 + c];
    s += v4 * wn[16 + c];
    s += v5 * wn[20 + c];
    s += v6 * wn[24 + c];
    y[c] = s;
  }
  const int bx = binof(v0), by = binof(v1);
  const int bid = by * NB1D + bx;
  sBid[t] = bid;
  __syncthreads();

  int rank = 0;
  for (int k = 0; k < 256; ++k)
    rank += (k < t && sBid[k] == bid) ? 1 : 0;  /* LDS broadcast loop */

#define EXCL(e) (sIncl[e] - (hPre[e] + hPost[e]))  /* e<=400 valid (zeros) */
  const int excl = EXCL(bid);
  const int slot = excl + hPre[bid] + rank;
  srec[slot * 2]     = make_float4(v0, v1, y[0], y[1]);
  srec[slot * 2 + 1] = make_float4(y[2], y[3], ci, __int_as_float(i));

  /* meta: fully-resolved 3x3 window descriptor (same formulas as sweep) */
  const int xlo = (bx > 0) ? bx - 1 : 0, xhi = (bx < 19) ? bx + 1 : 19;
  const int rm = by - 1, rp = by + 1;
  const int b0 = (rm >= 0) ? EXCL(rm * NB1D + xlo) : 0;
  const int e0 = (rm >= 0) ? EXCL(rm * NB1D + xhi + 1) : 0;
  const int b1 = EXCL(by * NB1D + xlo);
  const int e1 = EXCL(by * NB1D + xhi + 1);
  const int b2 = (rp < NB1D) ? EXCL(rp * NB1D + xlo) : 0;
  const int e2 = (rp < NB1D) ? EXCL(rp * NB1D + xhi + 1) : 0;
#undef EXCL
  const int len0 = e0 - b0, len1 = e1 - b1;
  const int l01 = len0 + len1;
  const int total = l01 + (e2 - b2);
  const int lens = len0 | (l01 << 14);           /* each <= 8192 < 2^14 */
  const unsigned ciorig = ((ci > 0.5f) ? 0x80000000u : 0u) | (unsigned)i;
  meta[slot * 2] = make_float4(__int_as_float(b0),
                               __int_as_float(b1 - len0),
                               __int_as_float(b2 - l01),
                               __int_as_float(lens));
  meta[slot * 2 + 1] = make_float4(v0, v1, __int_as_float((int)ciorig),
                                   __int_as_float(total));
}

// ---------------------------------------------------------------- K2 ------
// sweep (R13): front-end = two PARALLEL 16B loads of meta[s] (one 32B line)
// -- no self srec read, no bin calc, no binstart loads. Candidate loop,
// arithmetic order, WRED, epilogue identical to R12 -> bit-identical output.
// XCD-swizzled blockIdx; partials transposed [6][SWBLK]. No fences, no
// global atomics (R5/R8 lessons).
__global__ __launch_bounds__(256, 8) void sweep_kernel(
    const float* __restrict__ x, const float* __restrict__ wself,
    const float* __restrict__ bvec, const float4* __restrict__ meta,
    const float4* __restrict__ srec, float* __restrict__ out,
    float* __restrict__ partials)
{
  __shared__ float s_scal[4][6];
  const int lane = threadIdx.x & 63, wave = threadIdx.x >> 6;
  const int swz = (blockIdx.x & 7) * (SWBLK / 8) + (blockIdx.x >> 3);
  const int s = swz * 4 + wave;
  const float4 mA = meta[s * 2];
  const float4 mB = meta[s * 2 + 1];
  const int b0   = __float_as_int(mA.x);
  const int b1a  = __float_as_int(mA.y);
  const int b2a  = __float_as_int(mA.z);
  const int lens = __float_as_int(mA.w);
  const int len0 = lens & 0x3FFF, l01 = lens >> 14;
  const float px = mB.x, py = mB.y;
  const unsigned ciorig = (unsigned)__float_as_int(mB.z);
  const float ci = (ciorig >> 31) ? 1.0f : 0.0f;
  const int orig = (int)(ciorig & 0x7FFFFFFFu);
  const int total = __float_as_int(mB.w);

  /* ordinal o -> sorted index (2 cmp + 2 csel + add; wave-uniform lens) */
#define IA(O, DST) { \
    DST = ((O) < len0) ? (b0 + (O)) : (((O) < l01) ? (b1a + (O)) : (b2a + (O))); }

  float nsx = 0.f, nsy = 0.f, nsz = 0.f, nsw = 0.f;
  float pk = 0.f; /* cons*2^16 + cnb*2^8 + cnt (all <256 -> exact) */

  int o = lane;
  bool v = o < total;
  int ia; IA(v ? o : 0, ia); if (!v) ia = 0;
  float4 a0 = srec[ia * 2];
  float4 a1 = srec[ia * 2 + 1];
  const int nchunk = (total + 63) >> 6;
  for (int k = 0; k < nchunk; ++k) {
    int on = o + 64;
    bool vn = on < total;
    int ian; IA(vn ? on : 0, ian); if (!vn) ian = 0;
    float4 n0 = srec[ian * 2];          /* prefetch next chunk */
    float4 n1 = srec[ian * 2 + 1];
    float dx = __fsub_rn(px, a0.x), dy = __fsub_rn(py, a0.y);
    float d2 = __fadd_rn(__fmul_rn(dx, dx), __fmul_rn(dy, dy));
    bool valid = v && (__float_as_int(a1.w) != orig);
    bool inCR = valid && (d2 < CR2c);
    bool inR  = valid && (d2 < R2c);
    float cj = a1.z;
    pk += (inCR ? cj * 65536.f : 0.f) + (inR ? (cj * 256.f + 1.f) : 0.f);
    nsx += inR ? a0.z : 0.f;
    nsy += inR ? a0.w : 0.f;
    nsz += inR ? a1.x : 0.f;
    nsw += inR ? a1.y : 0.f;
    o = on; v = vn; a0 = n0; a1 = n1;
  }
#undef IA

  WRED(nsx); WRED(nsy); WRED(nsz); WRED(nsw); WRED(pk);

  if (lane == 0) {
    /* exact unpack (all fields integer-valued, < 2^24) */
    float consCR = floorf(pk * 1.52587890625e-05f);      /* 2^-16 */
    float rem = pk - consCR * 65536.f;
    float cnbR = floorf(rem * 0.00390625f);              /* 2^-8  */
    float cntR = rem - cnbR * 256.f;

    const float* xi = x + orig * 7;
    float vx = xi[2], vy = xi[3], typ = xi[4], x5 = xi[5], x6 = xi[6];
    float h0 = bvec[0] + px * wself[0] + py * wself[4] + vx * wself[8] +
               vy * wself[12] + typ * wself[16] + x5 * wself[20] +
               x6 * wself[24] + nsx;
    float h1 = bvec[1] + px * wself[1] + py * wself[5] + vx * wself[9] +
               vy * wself[13] + typ * wself[17] + x5 * wself[21] +
               x6 * wself[25] + nsy;
    float h2 = bvec[2] + px * wself[2] + py * wself[6] + vx * wself[10] +
               vy * wself[14] + typ * wself[18] + x5 * wself[22] +
               x6 * wself[26] + nsz;
    float h3 = bvec[3] + px * wself[3] + py * wself[7] + vx * wself[11] +
               vy * wself[15] + typ * wself[19] + x5 * wself[23] +
               x6 * wself[27] + nsw;
    float scm = ACCS * ci;
    h0 *= scm; h1 *= scm; h2 *= scm; h3 *= scm;
    float nvx = fminf(fmaxf(vx + h0, -MAXV), MAXV);
    float nvy = fminf(fmaxf(vy + h1, -MAXV), MAXV);
    float npx = px + nvx, npy = py + nvy;
    float border = 0.f;
    float ax = fabsf(npx), ay = fabsf(npy);
    if (ax > 1.0f) border += logf(ax + EPSV);
    if (ay > 1.0f) border += logf(ay + EPSV);
    bool dead = (ci > 0.5f) && (cnbR < 2.5f);
    bool consumed = (ci < 0.5f) && (consCR > 4.5f);
    float keep = (dead || consumed) ? 0.f : 1.f;
    float* orow = out + (size_t)orig * 7;
    orow[0] = npx * keep; orow[1] = npy * keep;
    orow[2] = nvx * keep; orow[3] = nvy * keep;
    orow[4] = typ * keep; orow[5] = h2 * keep; orow[6] = h3 * keep;
    s_scal[wave][0] = fabsf(nvx);
    s_scal[wave][1] = fabsf(nvy);
    s_scal[wave][2] = border;
    s_scal[wave][3] = consumed ? 1.f : 0.f;
    s_scal[wave][4] = dead ? 1.f : 0.f;
    s_scal[wave][5] = cntR - cnbR;
  }
  __syncthreads();
  if (threadIdx.x == 0) {
#pragma unroll
    for (int k = 0; k < 6; ++k)
      partials[k * SWBLK + swz] =
          s_scal[0][k] + s_scal[1][k] + s_scal[2][k] + s_scal[3][k];
  }
}

// ---------------------------------------------------------------- K3 ------
// Deterministic reduction, coalesced transposed partials (unchanged --
// summation order preserved for bit-identical scalars). Separate launch =
// cross-block visibility without fences (R5/R8 lessons).
__global__ __launch_bounds__(384) void reduce_kernel(
    const float* __restrict__ partials, float* __restrict__ out)
{
  int wave = threadIdx.x >> 6, lane = threadIdx.x & 63;
  if (wave >= 6) return;
  float s = 0.f;
  for (int bidx = lane; bidx < SWBLK; bidx += 64)
    s += partials[wave * SWBLK + bidx];
  WRED(s);
  if (lane == 0) {
    float v = s;
    if (wave < 2) v = s * (1.0f / 8192.0f); /* vel_bonus = mean */
    out[OUT_SCALARS + wave] = v;
  }
}

// ------------------------------------------------------------- launch -----
extern "C" void kernel_launch(void* const* d_in, const int* in_sizes, int n_in,
                              void* d_out, int out_size, void* d_ws, size_t ws_size,
                              hipStream_t stream)
{
  const float* x      = (const float*)d_in[0];
  const float* wself  = (const float*)d_in[1];
  const float* wneigh = (const float*)d_in[2];
  const float* bvec   = (const float*)d_in[3];
  float* out = (float*)d_out;
  float* ws  = (float*)d_ws;

  float4* srec  = (float4*)ws;                      /* 8N floats          */
  float4* meta  = (float4*)(ws + 8 * NPART);        /* 8N floats          */
  float* partials = ws + 16 * NPART;                /* 6*SWBLK floats     */

  hipLaunchKernelGGL(place_kernel, dim3(NPLACE), dim3(256), 0, stream,
                     x, wneigh, srec, meta);
  hipLaunchKernelGGL(sweep_kernel, dim3(SWBLK), dim3(256), 0, stream,
                     x, wself, bvec, meta, srec, out, partials);
  hipLaunchKernelGGL(reduce_kernel, dim3(1), dim3(384), 0, stream,
                     partials, out);
}